// Round 5
// baseline (445.715 us; speedup 1.0000x reference)
//
#include <hip/hip_runtime.h>
#include <hip/hip_fp16.h>

#define N_FEAT0 128
#define HID 64
#define NCLS 40

#define BSH 9            // log2 nodes per bucket
#define BSZ 512          // nodes per bucket
#define BCAP 12288       // slab capacity per bucket (mean 8192, sigma ~90 -> 45 sigma margin)
#define STILE 16384      // edges per scatter block

typedef _Float16 half8v __attribute__((ext_vector_type(8)));

// ---------------- phase 1: LDS-binned scatter of edges into per-bucket slabs ----
// Record = (d & 511) << 17 | s   (s < 2^17 since N = 100000 < 131072).
__global__ __launch_bounds__(256) void scatter_kernel(const int* __restrict__ esrc,
                                                      const int* __restrict__ edst,
                                                      int* __restrict__ bfill,
                                                      int* __restrict__ slab, int E) {
  __shared__ int cnt[256];
  __shared__ int base[256];
  int t = threadIdx.x;
  int t0 = blockIdx.x * STILE;
  cnt[t] = 0;
  __syncthreads();

  // pass A: histogram
#pragma unroll 4
  for (int i = 0; i < STILE / 1024; ++i) {
    int e = t0 + i * 1024 + t * 4;
    if (e < E) {
      int4 d4 = *(const int4*)(edst + e);
      atomicAdd(&cnt[d4.x >> BSH], 1);
      atomicAdd(&cnt[d4.y >> BSH], 1);
      atomicAdd(&cnt[d4.z >> BSH], 1);
      atomicAdd(&cnt[d4.w >> BSH], 1);
    }
  }
  __syncthreads();
  int c = cnt[t];
  if (c > 0) base[t] = t * BCAP + atomicAdd(&bfill[t], c);
  cnt[t] = 0;
  __syncthreads();

  // pass B: binned write (tile is L2-warm from pass A)
#pragma unroll 4
  for (int i = 0; i < STILE / 1024; ++i) {
    int e = t0 + i * 1024 + t * 4;
    if (e < E) {
      int4 s4 = *(const int4*)(esrc + e);
      int4 d4 = *(const int4*)(edst + e);
#define EMIT(dd, ss)                                             \
      {                                                          \
        int b_ = (dd) >> BSH;                                    \
        int r_ = atomicAdd(&cnt[b_], 1);                         \
        slab[base[b_] + r_] = (((dd) & (BSZ - 1)) << 17) | (ss); \
      }
      EMIT(d4.x, s4.x)
      EMIT(d4.y, s4.y)
      EMIT(d4.z, s4.z)
      EMIT(d4.w, s4.w)
#undef EMIT
    }
  }
}

// ---------------- phase 2: per-bucket CSR finalize (bscan merged in) ----------
// Each block re-scans the (<=256) bucket sizes in LDS to get its own output
// base -- deletes the separate bscan kernel and its inter-kernel gap.
__global__ __launch_bounds__(256) void build_kernel(const int* __restrict__ slab,
                                                    const int* __restrict__ bfill,
                                                    int* __restrict__ row_ptr,
                                                    float* __restrict__ dinv,
                                                    int* __restrict__ ew,
                                                    int N, int nbuck) {
  __shared__ int cnt[512];
  __shared__ int pre[512];
  __shared__ int s2[256];
  int b = blockIdx.x;
  int t = threadIdx.x;
  int nbase = b << BSH;
  int nNodes = N - nbase;
  if (nNodes > BSZ) nNodes = BSZ;

  // ---- in-block inclusive scan of bucket sizes -> obase ----
  s2[t] = (t < nbuck) ? bfill[t] : 0;
  __syncthreads();
  for (int off = 1; off < 256; off <<= 1) {
    int u = (t >= off) ? s2[t - off] : 0;
    __syncthreads();
    s2[t] += u;
    __syncthreads();
  }
  int sz = bfill[b];
  int obase = s2[b] - sz;           // exclusive prefix for this bucket
  if (b == 0 && t == 255) row_ptr[N] = s2[255];  // total == E
  __syncthreads();

  cnt[t] = 0;
  cnt[t + 256] = 0;
  __syncthreads();

  int sbeg = b * BCAP;

  // per-node histogram
  for (int r = t; r < sz; r += 256) atomicAdd(&cnt[((unsigned)slab[sbeg + r]) >> 17], 1);
  __syncthreads();

  // exclusive prefix over 512 counters (pair-sum + 256-wide scan)
  int a = cnt[2 * t], c = cnt[2 * t + 1];
  s2[t] = a + c;
  __syncthreads();
  for (int off = 1; off < 256; off <<= 1) {
    int u = (t >= off) ? s2[t - off] : 0;
    __syncthreads();
    s2[t] += u;
    __syncthreads();
  }
  int ex = s2[t] - (a + c);
  pre[2 * t] = ex;
  pre[2 * t + 1] = ex + a;
  __syncthreads();

  // row_ptr + dinv (coalesced)
  if (t < nNodes) {
    row_ptr[nbase + t] = obase + pre[t];
    dinv[nbase + t] = rsqrtf((float)(cnt[t] + 1));
  }
  int t2 = t + 256;
  if (t2 < nNodes) {
    row_ptr[nbase + t2] = obase + pre[t2];
    dinv[nbase + t2] = rsqrtf((float)(cnt[t2] + 1));
  }
  __syncthreads();
  cnt[t] = 0;
  cnt[t + 256] = 0;
  __syncthreads();

  // final permute: slab (coalesced read, L2-warm) -> node-ordered ew
  for (int r = t; r < sz; r += 256) {
    int rec = slab[sbeg + r];
    int dloc = ((unsigned)rec) >> 17;
    int rank = atomicAdd(&cnt[dloc], 1);
    ew[obase + pre[dloc] + rank] = rec & 0x1FFFF;
  }
}

// ---------------- dense GEMM with dinv row-scale epilogue, fp16 output -------
// Layer 0 only (f32 128-wide input x). G1 = (half) dinv (.) (x @ W0).
template <int K, int NC>
__global__ __launch_bounds__(256) void gemm_kernel(const float* __restrict__ A,
                                                   const float* __restrict__ W,
                                                   __half* __restrict__ Out,
                                                   const float* __restrict__ rowscale,
                                                   int N) {
  constexpr int BK = 64;
  constexpr int LDSS = 68;
  __shared__ float As[128 * LDSS];

  int t = threadIdx.x;
  int lane = t & 63;
  int wave = t >> 6;
  int c4 = lane & 15;
  int qr = lane >> 4;
  int r0 = blockIdx.x * 128;

  int wc = 4 * c4;
  if (wc > NC - 4) wc = NC - 4;
  bool cok = (wc == 4 * c4);

  float4 acc[8];
#pragma unroll
  for (int m = 0; m < 8; ++m) acc[m] = make_float4(0.f, 0.f, 0.f, 0.f);

  for (int kc = 0; kc < K; kc += BK) {
    __syncthreads();
#pragma unroll
    for (int i = 0; i < 8; ++i) {
      int idx = t + i * 256;
      int row = idx >> 4;
      int cq = idx & 15;
      int gr = r0 + row;
      if (gr >= N) gr = N - 1;
      float4 v = *(const float4*)(A + (size_t)gr * K + kc + 4 * cq);
      *(float4*)(As + row * LDSS + 4 * cq) = v;
    }
    __syncthreads();

#pragma unroll 2
    for (int kk = 0; kk < BK / 4; ++kk) {
      float4 w[4];
#pragma unroll
      for (int k = 0; k < 4; ++k)
        w[k] = *(const float4*)(W + (size_t)(kc + kk * 4 + k) * NC + wc);
#pragma unroll
      for (int m = 0; m < 8; ++m) {
        int lrow = wave * 32 + qr + 4 * m;
        float4 a = *(const float4*)(As + lrow * LDSS + kk * 4);
        acc[m].x = fmaf(a.x, w[0].x, acc[m].x);
        acc[m].y = fmaf(a.x, w[0].y, acc[m].y);
        acc[m].z = fmaf(a.x, w[0].z, acc[m].z);
        acc[m].w = fmaf(a.x, w[0].w, acc[m].w);
        acc[m].x = fmaf(a.y, w[1].x, acc[m].x);
        acc[m].y = fmaf(a.y, w[1].y, acc[m].y);
        acc[m].z = fmaf(a.y, w[1].z, acc[m].z);
        acc[m].w = fmaf(a.y, w[1].w, acc[m].w);
        acc[m].x = fmaf(a.z, w[2].x, acc[m].x);
        acc[m].y = fmaf(a.z, w[2].y, acc[m].y);
        acc[m].z = fmaf(a.z, w[2].z, acc[m].z);
        acc[m].w = fmaf(a.z, w[2].w, acc[m].w);
        acc[m].x = fmaf(a.w, w[3].x, acc[m].x);
        acc[m].y = fmaf(a.w, w[3].y, acc[m].y);
        acc[m].z = fmaf(a.w, w[3].z, acc[m].z);
        acc[m].w = fmaf(a.w, w[3].w, acc[m].w);
      }
    }
  }

  if (cok) {
#pragma unroll
    for (int m = 0; m < 8; ++m) {
      int gr = r0 + wave * 32 + qr + 4 * m;
      if (gr < N) {
        float ds = rowscale[gr];
        union { __half2 h[2]; uint2 u; } cv;
        cv.h[0] = __floats2half2_rn(ds * acc[m].x, ds * acc[m].y);
        cv.h[1] = __floats2half2_rn(ds * acc[m].z, ds * acc[m].w);
        *(uint2*)(Out + (size_t)gr * NC + wc) = cv.u;
      }
    }
  }
}

// ---------------- fused agg + GEMV (register-fixed) ----------------
// G_out = dinv (.) (relu(dinv (.) A_hat G_in) @ W).  Round-5 fixes round-4's
// regression: W fragment lives in 8 NAMED fp16 ext-vector registers (32 VGPR,
// round-4's f32 w[8][8] array was spilled/rematerialized -- VGPR_Count=56 < 64
// proved it never was register-resident). Grid 3200 blocks (2x oversubscribed,
// ~8 contiguous nodes/wave) restores backfill dynamics; row_ptr chained.
template <int NC>
__global__ __launch_bounds__(256) void fused_kernel(const __half* __restrict__ Gin,
                                                    const int* __restrict__ row_ptr,
                                                    const int* __restrict__ ew,
                                                    const float* __restrict__ dinv,
                                                    const float* __restrict__ W,
                                                    __half* __restrict__ Gout, int N) {
  int lane = threadIdx.x & 63;
  int eg = lane >> 3;                // edge slot / output col-block
  int fo = lane & 7;                 // feature oct
  int wid = (blockIdx.x << 2) + (threadIdx.x >> 6);
  int NW = gridDim.x << 2;
  int c0 = eg * 8;

  // W fragment: w_i[j] = W[fo*8+i][c0+j] as fp16 (8 named half8v = 32 VGPR)
  half8v w0, w1, w2, w3, w4, w5, w6, w7;
#define WE(base, j) (((c0 + (j)) < NC) ? (_Float16)W[(base) + (j)] : (_Float16)0.f)
#define LDW(i)                                                                   \
  {                                                                              \
    int base = (fo * 8 + (i)) * NC + c0;                                         \
    w##i = (half8v){WE(base, 0), WE(base, 1), WE(base, 2), WE(base, 3),          \
                    WE(base, 4), WE(base, 5), WE(base, 6), WE(base, 7)};         \
  }
  LDW(0) LDW(1) LDW(2) LDW(3) LDW(4) LDW(5) LDW(6) LDW(7)
#undef LDW
#undef WE

  int npw = (N + NW - 1) / NW;
  int v0 = wid * npw;
  int v1 = v0 + npw;
  if (v1 > N) v1 = N;
  if (v0 >= v1) return;

  int beg = __builtin_amdgcn_readfirstlane(row_ptr[v0]);
  for (int v = v0; v < v1; ++v) {
    int end = __builtin_amdgcn_readfirstlane(row_ptr[v + 1]);
    float acc[8];
#pragma unroll
    for (int i = 0; i < 8; ++i) acc[i] = 0.f;

#define GLD(s) (*(const uint4*)(Gin + (size_t)(s) * 64 + fo * 8))
    auto addrow = [&](uint4 q) {
      const __half2* h2 = (const __half2*)&q;
#pragma unroll
      for (int i = 0; i < 4; ++i) {
        float2 f2 = __half22float2(h2[i]);
        acc[2 * i] += f2.x;
        acc[2 * i + 1] += f2.y;
      }
    };

    if (eg == 0) addrow(GLD(v));     // self-loop term
    int j = beg;
    for (; j + 16 <= end; j += 16) {
      int s0 = ew[j + eg];
      int s1 = ew[j + 8 + eg];
      uint4 a = GLD(s0);
      uint4 b = GLD(s1);
      addrow(a);
      addrow(b);
    }
    if (j + 8 <= end) {
      addrow(GLD(ew[j + eg]));
      j += 8;
    }
    {
      int idx = j + eg;
      if (idx < end) addrow(GLD(ew[idx]));
    }
#undef GLD

    // fold edge-slot groups (lane bits 3..5): lane now holds agg[fo*8..fo*8+7]
#pragma unroll
    for (int m = 8; m <= 32; m <<= 1)
#pragma unroll
      for (int i = 0; i < 8; ++i) acc[i] += __shfl_xor(acc[i], m);

    float dv = dinv[v];
    float pj0 = 0.f, pj1 = 0.f, pj2 = 0.f, pj3 = 0.f;
    float pj4 = 0.f, pj5 = 0.f, pj6 = 0.f, pj7 = 0.f;
#define GROW(i)                                       \
    {                                                 \
      float hi = fmaxf(dv * acc[i], 0.f);             \
      pj0 = fmaf(hi, (float)w##i[0], pj0);            \
      pj1 = fmaf(hi, (float)w##i[1], pj1);            \
      pj2 = fmaf(hi, (float)w##i[2], pj2);            \
      pj3 = fmaf(hi, (float)w##i[3], pj3);            \
      pj4 = fmaf(hi, (float)w##i[4], pj4);            \
      pj5 = fmaf(hi, (float)w##i[5], pj5);            \
      pj6 = fmaf(hi, (float)w##i[6], pj6);            \
      pj7 = fmaf(hi, (float)w##i[7], pj7);            \
    }
    GROW(0) GROW(1) GROW(2) GROW(3) GROW(4) GROW(5) GROW(6) GROW(7)
#undef GROW
    // fold feature octs (lane bits 0..2)
#define PFOLD(m)                                                          \
    pj0 += __shfl_xor(pj0, m); pj1 += __shfl_xor(pj1, m);                 \
    pj2 += __shfl_xor(pj2, m); pj3 += __shfl_xor(pj3, m);                 \
    pj4 += __shfl_xor(pj4, m); pj5 += __shfl_xor(pj5, m);                 \
    pj6 += __shfl_xor(pj6, m); pj7 += __shfl_xor(pj7, m);
    PFOLD(1) PFOLD(2) PFOLD(4)
#undef PFOLD

    if (fo == 0 && c0 < NC) {
      union { __half2 h2[4]; uint4 u; } cv;
      cv.h2[0] = __floats2half2_rn(dv * pj0, dv * pj1);
      cv.h2[1] = __floats2half2_rn(dv * pj2, dv * pj3);
      cv.h2[2] = __floats2half2_rn(dv * pj4, dv * pj5);
      cv.h2[3] = __floats2half2_rn(dv * pj6, dv * pj7);
      *(uint4*)(Gout + (size_t)v * NC + c0) = cv.u;  // 16B aligned (NC*2 % 16 == 0)
    }
    beg = end;
  }
}

// ---------------- final sparse aggregation (f32 output) ----------------
template <int F>
__global__ __launch_bounds__(256) void agg_kernel(const __half* __restrict__ G,
                                                  const int* __restrict__ row_ptr,
                                                  const int* __restrict__ ew,
                                                  const float* __restrict__ dinv,
                                                  float* __restrict__ Hout, int N) {
  constexpr int FO = F / 8;
  int gid = blockIdx.x * blockDim.x + threadIdx.x;
  int v = gid >> 6;
  if (v >= N) return;
  int lane = threadIdx.x & 63;
  int eg = lane >> 3;
  int fo = lane & 7;
  bool fok = (fo < FO);
  int foc = fok ? fo : FO - 1;

  float acc[8];
#pragma unroll
  for (int i = 0; i < 8; ++i) acc[i] = 0.f;

#define GLD(s) (*(const uint4*)(G + (size_t)(s) * F + foc * 8))
  auto addrow = [&](uint4 q) {
    const __half2* h = (const __half2*)&q;
#pragma unroll
    for (int i = 0; i < 4; ++i) {
      float2 f = __half22float2(h[i]);
      acc[2 * i] += f.x;
      acc[2 * i + 1] += f.y;
    }
  };

  if (eg == 0) addrow(GLD(v));

  int beg = __builtin_amdgcn_readfirstlane(row_ptr[v]);
  int end = __builtin_amdgcn_readfirstlane(row_ptr[v + 1]);
  int j = beg;
  for (; j + 16 <= end; j += 16) {
    int s0 = ew[j + eg];
    int s1 = ew[j + 8 + eg];
    uint4 a = GLD(s0);
    uint4 b = GLD(s1);
    addrow(a);
    addrow(b);
  }
  if (j + 8 <= end) {
    addrow(GLD(ew[j + eg]));
    j += 8;
  }
  {
    int idx = j + eg;
    if (idx < end) addrow(GLD(ew[idx]));
  }
#undef GLD

#pragma unroll
  for (int m = 8; m <= 32; m <<= 1) {
#pragma unroll
    for (int i = 0; i < 8; ++i) acc[i] += __shfl_xor(acc[i], m);
  }

  if (fok) {
    float dv = dinv[v];
    float4 o0, o1;
    o0.x = fmaxf(dv * acc[0], 0.f);
    o0.y = fmaxf(dv * acc[1], 0.f);
    o0.z = fmaxf(dv * acc[2], 0.f);
    o0.w = fmaxf(dv * acc[3], 0.f);
    o1.x = fmaxf(dv * acc[4], 0.f);
    o1.y = fmaxf(dv * acc[5], 0.f);
    o1.z = fmaxf(dv * acc[6], 0.f);
    o1.w = fmaxf(dv * acc[7], 0.f);
    float4* outp = (float4*)(Hout + (size_t)v * F + fo * 8);
    outp[0] = o0;
    outp[1] = o1;
  }
}

extern "C" void kernel_launch(void* const* d_in, const int* in_sizes, int n_in,
                              void* d_out, int out_size, void* d_ws, size_t ws_size,
                              hipStream_t stream) {
  const float* x  = (const float*)d_in[0];
  const int*   eg = (const int*)d_in[1];
  const float* W0 = (const float*)d_in[2];
  const float* W1 = (const float*)d_in[3];
  const float* W2 = (const float*)d_in[4];
  float* out = (float*)d_out;

  const int N = in_sizes[0] / N_FEAT0;  // 100000
  const int E = in_sizes[1] / 2;        // 1600000
  const int* esrc = eg;
  const int* edst = eg + E;
  const int nbuck = (N + BSZ - 1) >> BSH;  // 196

  // workspace layout (256B aligned)
  char* p = (char*)d_ws;
  auto alloc = [&](size_t bytes) {
    char* r = p;
    p += (bytes + 255) & ~(size_t)255;
    return r;
  };
  int*    bfill   = (int*)alloc(256 * 4);
  int*    row_ptr = (int*)alloc((size_t)(N + 1) * 4);
  float*  dinv    = (float*)alloc((size_t)N * 4);
  int*    ew      = (int*)alloc((size_t)E * 4);
  __half* bufG1   = (__half*)alloc((size_t)N * HID * 2);   // 12.8 MB
  __half* bufG2   = (__half*)alloc((size_t)N * HID * 2);   // 12.8 MB
  __half* bufG3   = (__half*)alloc((size_t)N * NCLS * 2);  // 8 MB
  // slab aliases bufG1 (9.63 MB <= 12.8 MB); build reads it before gemm0
  // writes bufG1 (stream-ordered).
  int* slab = (int*)bufG1;

  hipMemsetAsync(bfill, 0, 256 * 4, stream);

  const int sblocks = (E + STILE - 1) / STILE;  // 98
  scatter_kernel<<<sblocks, 256, 0, stream>>>(esrc, edst, bfill, slab, E);
  build_kernel<<<nbuck, 256, 0, stream>>>(slab, bfill, row_ptr, dinv, ew, N, nbuck);

  const int gblocks = (N + 127) / 128;
  const int ablocks = (N + 3) / 4;
  const int fblocks = 3200;  // 12800 waves, ~8 contiguous nodes each (backfill)
  // layer 0: 128 -> 64 (dense)
  gemm_kernel<128, 64><<<gblocks, 256, 0, stream>>>(x, W0, bufG1, dinv, N);
  // layer 1: agg + (64 -> 64) fused
  fused_kernel<64><<<fblocks, 256, 0, stream>>>(bufG1, row_ptr, ew, dinv, W1, bufG2, N);
  // layer 2: agg + (64 -> 40) fused
  fused_kernel<40><<<fblocks, 256, 0, stream>>>(bufG2, row_ptr, ew, dinv, W2, bufG3, N);
  // final aggregation -> output
  agg_kernel<40><<<ablocks, 256, 0, stream>>>(bufG3, row_ptr, ew, dinv, out, N);
}

// Round 6
// 346.264 us; speedup vs baseline: 1.2872x; 1.2872x over previous
//
#include <hip/hip_runtime.h>
#include <hip/hip_fp16.h>

#define N_FEAT0 128
#define HID 64
#define NCLS 40

#define BSH 9            // log2 nodes per bucket
#define BSZ 512          // nodes per bucket
#define BCAP 12288       // slab capacity per bucket (mean 8192, sigma ~90 -> 45 sigma margin)
#define STILE 16384      // edges per scatter block

// ---------------- phase 1: LDS-binned scatter of edges into per-bucket slabs ----
// Record = (d & 511) << 17 | s   (s < 2^17 since N = 100000 < 131072).
__global__ __launch_bounds__(256) void scatter_kernel(const int* __restrict__ esrc,
                                                      const int* __restrict__ edst,
                                                      int* __restrict__ bfill,
                                                      int* __restrict__ slab, int E) {
  __shared__ int cnt[256];
  __shared__ int base[256];
  int t = threadIdx.x;
  int t0 = blockIdx.x * STILE;
  cnt[t] = 0;
  __syncthreads();

  // pass A: histogram
#pragma unroll 4
  for (int i = 0; i < STILE / 1024; ++i) {
    int e = t0 + i * 1024 + t * 4;
    if (e < E) {
      int4 d4 = *(const int4*)(edst + e);
      atomicAdd(&cnt[d4.x >> BSH], 1);
      atomicAdd(&cnt[d4.y >> BSH], 1);
      atomicAdd(&cnt[d4.z >> BSH], 1);
      atomicAdd(&cnt[d4.w >> BSH], 1);
    }
  }
  __syncthreads();
  int c = cnt[t];
  if (c > 0) base[t] = t * BCAP + atomicAdd(&bfill[t], c);
  cnt[t] = 0;
  __syncthreads();

  // pass B: binned write (tile is L2-warm from pass A)
#pragma unroll 4
  for (int i = 0; i < STILE / 1024; ++i) {
    int e = t0 + i * 1024 + t * 4;
    if (e < E) {
      int4 s4 = *(const int4*)(esrc + e);
      int4 d4 = *(const int4*)(edst + e);
#define EMIT(dd, ss)                                             \
      {                                                          \
        int b_ = (dd) >> BSH;                                    \
        int r_ = atomicAdd(&cnt[b_], 1);                         \
        slab[base[b_] + r_] = (((dd) & (BSZ - 1)) << 17) | (ss); \
      }
      EMIT(d4.x, s4.x)
      EMIT(d4.y, s4.y)
      EMIT(d4.z, s4.z)
      EMIT(d4.w, s4.w)
#undef EMIT
    }
  }
}

// ---------------- phase 2: per-bucket CSR finalize (bscan merged in) ----------
// Each block re-scans the (<=256) bucket sizes in LDS to get its own output
// base -- no separate bscan kernel. Verified correct in rounds 4-5.
__global__ __launch_bounds__(256) void build_kernel(const int* __restrict__ slab,
                                                    const int* __restrict__ bfill,
                                                    int* __restrict__ row_ptr,
                                                    float* __restrict__ dinv,
                                                    int* __restrict__ ew,
                                                    int N, int nbuck) {
  __shared__ int cnt[512];
  __shared__ int pre[512];
  __shared__ int s2[256];
  int b = blockIdx.x;
  int t = threadIdx.x;
  int nbase = b << BSH;
  int nNodes = N - nbase;
  if (nNodes > BSZ) nNodes = BSZ;

  // ---- in-block inclusive scan of bucket sizes -> obase ----
  s2[t] = (t < nbuck) ? bfill[t] : 0;
  __syncthreads();
  for (int off = 1; off < 256; off <<= 1) {
    int u = (t >= off) ? s2[t - off] : 0;
    __syncthreads();
    s2[t] += u;
    __syncthreads();
  }
  int sz = bfill[b];
  int obase = s2[b] - sz;           // exclusive prefix for this bucket
  if (b == 0 && t == 255) row_ptr[N] = s2[255];  // total == E
  __syncthreads();

  cnt[t] = 0;
  cnt[t + 256] = 0;
  __syncthreads();

  int sbeg = b * BCAP;

  // per-node histogram
  for (int r = t; r < sz; r += 256) atomicAdd(&cnt[((unsigned)slab[sbeg + r]) >> 17], 1);
  __syncthreads();

  // exclusive prefix over 512 counters (pair-sum + 256-wide scan)
  int a = cnt[2 * t], c = cnt[2 * t + 1];
  s2[t] = a + c;
  __syncthreads();
  for (int off = 1; off < 256; off <<= 1) {
    int u = (t >= off) ? s2[t - off] : 0;
    __syncthreads();
    s2[t] += u;
    __syncthreads();
  }
  int ex = s2[t] - (a + c);
  pre[2 * t] = ex;
  pre[2 * t + 1] = ex + a;
  __syncthreads();

  // row_ptr + dinv (coalesced)
  if (t < nNodes) {
    row_ptr[nbase + t] = obase + pre[t];
    dinv[nbase + t] = rsqrtf((float)(cnt[t] + 1));
  }
  int t2 = t + 256;
  if (t2 < nNodes) {
    row_ptr[nbase + t2] = obase + pre[t2];
    dinv[nbase + t2] = rsqrtf((float)(cnt[t2] + 1));
  }
  __syncthreads();
  cnt[t] = 0;
  cnt[t + 256] = 0;
  __syncthreads();

  // final permute: slab (coalesced read, L2-warm) -> node-ordered ew
  for (int r = t; r < sz; r += 256) {
    int rec = slab[sbeg + r];
    int dloc = ((unsigned)rec) >> 17;
    int rank = atomicAdd(&cnt[dloc], 1);
    ew[obase + pre[dloc] + rank] = rec & 0x1FFFF;
  }
}

// ---------------- layer-0 dense GEMM (f32 in, fp16 out, dinv epilogue) -------
template <int K, int NC>
__global__ __launch_bounds__(256) void gemm_kernel(const float* __restrict__ A,
                                                   const float* __restrict__ W,
                                                   __half* __restrict__ Out,
                                                   const float* __restrict__ rowscale,
                                                   int N) {
  constexpr int BK = 64;
  constexpr int LDSS = 68;
  __shared__ float As[128 * LDSS];

  int t = threadIdx.x;
  int lane = t & 63;
  int wave = t >> 6;
  int c4 = lane & 15;
  int qr = lane >> 4;
  int r0 = blockIdx.x * 128;

  int wc = 4 * c4;
  if (wc > NC - 4) wc = NC - 4;
  bool cok = (wc == 4 * c4);

  float4 acc[8];
#pragma unroll
  for (int m = 0; m < 8; ++m) acc[m] = make_float4(0.f, 0.f, 0.f, 0.f);

  for (int kc = 0; kc < K; kc += BK) {
    __syncthreads();
#pragma unroll
    for (int i = 0; i < 8; ++i) {
      int idx = t + i * 256;
      int row = idx >> 4;
      int cq = idx & 15;
      int gr = r0 + row;
      if (gr >= N) gr = N - 1;
      float4 v = *(const float4*)(A + (size_t)gr * K + kc + 4 * cq);
      *(float4*)(As + row * LDSS + 4 * cq) = v;
    }
    __syncthreads();

#pragma unroll 2
    for (int kk = 0; kk < BK / 4; ++kk) {
      float4 w[4];
#pragma unroll
      for (int k = 0; k < 4; ++k)
        w[k] = *(const float4*)(W + (size_t)(kc + kk * 4 + k) * NC + wc);
#pragma unroll
      for (int m = 0; m < 8; ++m) {
        int lrow = wave * 32 + qr + 4 * m;
        float4 a = *(const float4*)(As + lrow * LDSS + kk * 4);
        acc[m].x = fmaf(a.x, w[0].x, acc[m].x);
        acc[m].y = fmaf(a.x, w[0].y, acc[m].y);
        acc[m].z = fmaf(a.x, w[0].z, acc[m].z);
        acc[m].w = fmaf(a.x, w[0].w, acc[m].w);
        acc[m].x = fmaf(a.y, w[1].x, acc[m].x);
        acc[m].y = fmaf(a.y, w[1].y, acc[m].y);
        acc[m].z = fmaf(a.y, w[1].z, acc[m].z);
        acc[m].w = fmaf(a.y, w[1].w, acc[m].w);
        acc[m].x = fmaf(a.z, w[2].x, acc[m].x);
        acc[m].y = fmaf(a.z, w[2].y, acc[m].y);
        acc[m].z = fmaf(a.z, w[2].z, acc[m].z);
        acc[m].w = fmaf(a.z, w[2].w, acc[m].w);
        acc[m].x = fmaf(a.w, w[3].x, acc[m].x);
        acc[m].y = fmaf(a.w, w[3].y, acc[m].y);
        acc[m].z = fmaf(a.w, w[3].z, acc[m].z);
        acc[m].w = fmaf(a.w, w[3].w, acc[m].w);
      }
    }
  }

  if (cok) {
#pragma unroll
    for (int m = 0; m < 8; ++m) {
      int gr = r0 + wave * 32 + qr + 4 * m;
      if (gr < N) {
        float ds = rowscale[gr];
        union { __half2 h[2]; uint2 u; } cv;
        cv.h[0] = __floats2half2_rn(ds * acc[m].x, ds * acc[m].y);
        cv.h[1] = __floats2half2_rn(ds * acc[m].z, ds * acc[m].w);
        *(uint2*)(Out + (size_t)gr * NC + wc) = cv.u;
      }
    }
  }
}

// ---------------- hidden-layer GEMM: fp16 A (K=64), f32 W, fp16 out ----------
// fp16 A halves the A-read (25.6 -> 12.8 MB) and the LDS tile; single K-chunk
// (K == 64), half8 LDS reads unpacked via __half22float2 in the FMA loop.
template <int NC>
__global__ __launch_bounds__(256) void gemm_h_kernel(const __half* __restrict__ A,
                                                     const float* __restrict__ W,
                                                     __half* __restrict__ Out,
                                                     const float* __restrict__ rowscale,
                                                     int N) {
  constexpr int K = 64;
  constexpr int LDSH = 76;            // halves per row (+12 pad): 2-way max on writes
  __shared__ __half As[128 * LDSH];   // 19456 B

  int t = threadIdx.x;
  int lane = t & 63;
  int wave = t >> 6;
  int c4 = lane & 15;
  int qr = lane >> 4;
  int r0 = blockIdx.x * 128;

  int wc = 4 * c4;
  if (wc > NC - 4) wc = NC - 4;
  bool cok = (wc == 4 * c4);

  float4 acc[8];
#pragma unroll
  for (int m = 0; m < 8; ++m) acc[m] = make_float4(0.f, 0.f, 0.f, 0.f);

  // stage A[r0..r0+127][0..63] fp16: 4 x uint4 per thread, coalesced
#pragma unroll
  for (int i = 0; i < 4; ++i) {
    int idx = t + i * 256;            // 0..1023
    int row = idx >> 3;               // 0..127
    int cq = idx & 7;                 // oct of 8 halves
    int gr = r0 + row;
    if (gr >= N) gr = N - 1;
    uint4 v = *(const uint4*)(A + (size_t)gr * K + cq * 8);
    *(uint4*)(As + row * LDSH + cq * 8) = v;
  }
  __syncthreads();

#pragma unroll 2
  for (int kk = 0; kk < 8; ++kk) {    // 8 k-elems per step
    float4 w[8];
#pragma unroll
    for (int k = 0; k < 8; ++k)
      w[k] = *(const float4*)(W + (size_t)(kk * 8 + k) * NC + wc);
#pragma unroll
    for (int m = 0; m < 8; ++m) {
      int lrow = wave * 32 + qr + 4 * m;
      uint4 av = *(const uint4*)(As + lrow * LDSH + kk * 8);
      const __half2* h2 = (const __half2*)&av;
      float2 f0 = __half22float2(h2[0]);
      float2 f1 = __half22float2(h2[1]);
      float2 f2 = __half22float2(h2[2]);
      float2 f3 = __half22float2(h2[3]);
#define FMA4(aa, ww)                              \
      acc[m].x = fmaf(aa, ww.x, acc[m].x);        \
      acc[m].y = fmaf(aa, ww.y, acc[m].y);        \
      acc[m].z = fmaf(aa, ww.z, acc[m].z);        \
      acc[m].w = fmaf(aa, ww.w, acc[m].w);
      FMA4(f0.x, w[0]) FMA4(f0.y, w[1])
      FMA4(f1.x, w[2]) FMA4(f1.y, w[3])
      FMA4(f2.x, w[4]) FMA4(f2.y, w[5])
      FMA4(f3.x, w[6]) FMA4(f3.y, w[7])
#undef FMA4
    }
  }

  if (cok) {
#pragma unroll
    for (int m = 0; m < 8; ++m) {
      int gr = r0 + wave * 32 + qr + 4 * m;
      if (gr < N) {
        float ds = rowscale[gr];
        union { __half2 h[2]; uint2 u; } cv;
        cv.h[0] = __floats2half2_rn(ds * acc[m].x, ds * acc[m].y);
        cv.h[1] = __floats2half2_rn(ds * acc[m].z, ds * acc[m].w);
        *(uint2*)(Out + (size_t)gr * NC + wc) = cv.u;
      }
    }
  }
}

// ---------------- sparse aggregation: one wave per node, fp16 gather ---------
// Lanes = 8 edge-slots x 8 feature-octs; dwordx4 gathers 8 full rows (1 KB).
// f32 accumulate, 3-level shfl_xor fold. HOUT: fp16 output (hidden layers),
// else f32 (final layer).
template <int F, bool HOUT>
__global__ __launch_bounds__(256) void agg_kernel(const __half* __restrict__ G,
                                                  const int* __restrict__ row_ptr,
                                                  const int* __restrict__ ew,
                                                  const float* __restrict__ dinv,
                                                  void* __restrict__ HoutV, int N) {
  constexpr int FO = F / 8;
  int gid = blockIdx.x * blockDim.x + threadIdx.x;
  int v = gid >> 6;
  if (v >= N) return;
  int lane = threadIdx.x & 63;
  int eg = lane >> 3;
  int fo = lane & 7;
  bool fok = (fo < FO);
  int foc = fok ? fo : FO - 1;

  float acc[8];
#pragma unroll
  for (int i = 0; i < 8; ++i) acc[i] = 0.f;

#define GLD(s) (*(const uint4*)(G + (size_t)(s) * F + foc * 8))
  auto addrow = [&](uint4 q) {
    const __half2* h = (const __half2*)&q;
#pragma unroll
    for (int i = 0; i < 4; ++i) {
      float2 f = __half22float2(h[i]);
      acc[2 * i] += f.x;
      acc[2 * i + 1] += f.y;
    }
  };

  if (eg == 0) addrow(GLD(v));       // self-loop term

  int beg = __builtin_amdgcn_readfirstlane(row_ptr[v]);
  int end = __builtin_amdgcn_readfirstlane(row_ptr[v + 1]);
  int j = beg;
  for (; j + 16 <= end; j += 16) {
    int s0 = ew[j + eg];
    int s1 = ew[j + 8 + eg];
    uint4 a = GLD(s0);
    uint4 b = GLD(s1);
    addrow(a);
    addrow(b);
  }
  if (j + 8 <= end) {
    addrow(GLD(ew[j + eg]));
    j += 8;
  }
  {
    int idx = j + eg;
    if (idx < end) addrow(GLD(ew[idx]));
  }
#undef GLD

#pragma unroll
  for (int m = 8; m <= 32; m <<= 1) {
#pragma unroll
    for (int i = 0; i < 8; ++i) acc[i] += __shfl_xor(acc[i], m);
  }

  if (fok) {
    float dv = dinv[v];
    if constexpr (HOUT) {
      __half* Hout = (__half*)HoutV;
      union { __half2 h2[4]; uint4 u; } cv;
      cv.h2[0] = __floats2half2_rn(fmaxf(dv * acc[0], 0.f), fmaxf(dv * acc[1], 0.f));
      cv.h2[1] = __floats2half2_rn(fmaxf(dv * acc[2], 0.f), fmaxf(dv * acc[3], 0.f));
      cv.h2[2] = __floats2half2_rn(fmaxf(dv * acc[4], 0.f), fmaxf(dv * acc[5], 0.f));
      cv.h2[3] = __floats2half2_rn(fmaxf(dv * acc[6], 0.f), fmaxf(dv * acc[7], 0.f));
      *(uint4*)(Hout + (size_t)v * F + fo * 8) = cv.u;
    } else {
      float* Hout = (float*)HoutV;
      float4 o0, o1;
      o0.x = fmaxf(dv * acc[0], 0.f);
      o0.y = fmaxf(dv * acc[1], 0.f);
      o0.z = fmaxf(dv * acc[2], 0.f);
      o0.w = fmaxf(dv * acc[3], 0.f);
      o1.x = fmaxf(dv * acc[4], 0.f);
      o1.y = fmaxf(dv * acc[5], 0.f);
      o1.z = fmaxf(dv * acc[6], 0.f);
      o1.w = fmaxf(dv * acc[7], 0.f);
      float4* outp = (float4*)(Hout + (size_t)v * F + fo * 8);
      outp[0] = o0;
      outp[1] = o1;
    }
  }
}

extern "C" void kernel_launch(void* const* d_in, const int* in_sizes, int n_in,
                              void* d_out, int out_size, void* d_ws, size_t ws_size,
                              hipStream_t stream) {
  const float* x  = (const float*)d_in[0];
  const int*   eg = (const int*)d_in[1];
  const float* W0 = (const float*)d_in[2];
  const float* W1 = (const float*)d_in[3];
  const float* W2 = (const float*)d_in[4];
  float* out = (float*)d_out;

  const int N = in_sizes[0] / N_FEAT0;  // 100000
  const int E = in_sizes[1] / 2;        // 1600000
  const int* esrc = eg;
  const int* edst = eg + E;
  const int nbuck = (N + BSZ - 1) >> BSH;  // 196

  // workspace layout (256B aligned)
  char* p = (char*)d_ws;
  auto alloc = [&](size_t bytes) {
    char* r = p;
    p += (bytes + 255) & ~(size_t)255;
    return r;
  };
  int*    bfill   = (int*)alloc(256 * 4);
  int*    row_ptr = (int*)alloc((size_t)(N + 1) * 4);
  float*  dinv    = (float*)alloc((size_t)N * 4);
  int*    ew      = (int*)alloc((size_t)E * 4);
  __half* bufG    = (__half*)alloc((size_t)N * HID * 2);   // 12.8 MB (G1, then G2)
  __half* bufH    = (__half*)alloc((size_t)N * HID * 2);   // 12.8 MB (H1, then H2)
  __half* bufG3   = (__half*)alloc((size_t)N * NCLS * 2);  // 8 MB
  // slab aliases bufH (9.63 MB <= 12.8 MB); build reads it before agg1 writes
  // bufH (stream-ordered).
  int* slab = (int*)bufH;

  hipMemsetAsync(bfill, 0, 256 * 4, stream);

  const int sblocks = (E + STILE - 1) / STILE;  // 98
  scatter_kernel<<<sblocks, 256, 0, stream>>>(esrc, edst, bfill, slab, E);
  build_kernel<<<nbuck, 256, 0, stream>>>(slab, bfill, row_ptr, dinv, ew, N, nbuck);

  const int gblocks = (N + 127) / 128;
  const int ablocks = (N + 3) / 4;
  // layer 0: 128 -> 64 (dense, f32 in)
  gemm_kernel<128, 64><<<gblocks, 256, 0, stream>>>(x, W0, bufG, dinv, N);
  agg_kernel<64, true><<<ablocks, 256, 0, stream>>>(bufG, row_ptr, ew, dinv, bufH, N);
  // layer 1: 64 -> 64 (fp16 in)
  gemm_h_kernel<64><<<gblocks, 256, 0, stream>>>(bufH, W1, bufG, dinv, N);
  agg_kernel<64, true><<<ablocks, 256, 0, stream>>>(bufG, row_ptr, ew, dinv, bufH, N);
  // layer 2: 64 -> 40 (fp16 in)
  gemm_h_kernel<40><<<gblocks, 256, 0, stream>>>(bufH, W2, bufG3, dinv, N);
  agg_kernel<40, false><<<ablocks, 256, 0, stream>>>(bufG3, row_ptr, ew, dinv, out, N);
}